// Round 2
// baseline (679.330 us; speedup 1.0000x reference)
//
#include <hip/hip_runtime.h>

// out[b,j,p] = sum_d x[b, nfj[j], d] * W[j,p,d] + bias[j,p]
// B=16384, N=32, D=256, J=23, P=2. Memory-bound: ~386 MB x-read floor (~62 us).
//
// R2 structure: grid = (B/64, J). j is block-uniform -> W/bias/nfj loads are
// wave-uniform (scalar base, L1 broadcast). Each 16-lane group handles 4
// consecutive b for one j: each W float4 is loaded once and reused for 4 x
// rows (W:x traffic 1:4 instead of 2:1 in R1).

constexpr int Bn = 16384;
constexpr int Nn = 32;
constexpr int Dn = 256;
constexpr int Jn = 23;
constexpr int Pn = 2;

__device__ __forceinline__ float dot4(float4 a, float4 b) {
    return a.x * b.x + a.y * b.y + a.z * b.z + a.w * b.w;
}

__global__ __launch_bounds__(256) void detok_kernel(
    const float* __restrict__ x, const float* __restrict__ W,
    const float* __restrict__ bias, const int* __restrict__ nfj,
    float* __restrict__ out)
{
    const int j    = blockIdx.y;          // block-uniform joint
    const int node = nfj[j];              // scalar load (uniform)
    const int lane = threadIdx.x & 63;
    const int wid  = threadIdx.x >> 6;    // wave in block, 0..3
    const int grp  = lane >> 4;           // 16-lane group in wave, 0..3
    const int gl   = lane & 15;           // lane within group

    // block covers 64 b values; each group takes 4 consecutive b.
    const int b0 = (blockIdx.x * 16 + wid * 4 + grp) * 4;

    const float4* __restrict__ w0 =
        reinterpret_cast<const float4*>(W + ((size_t)j * Pn + 0) * Dn);
    const float4* __restrict__ w1 =
        reinterpret_cast<const float4*>(W + ((size_t)j * Pn + 1) * Dn);

    const float4* __restrict__ xr0 =
        reinterpret_cast<const float4*>(x + ((size_t)(b0 + 0) * Nn + node) * Dn);
    const float4* __restrict__ xr1 =
        reinterpret_cast<const float4*>(x + ((size_t)(b0 + 1) * Nn + node) * Dn);
    const float4* __restrict__ xr2 =
        reinterpret_cast<const float4*>(x + ((size_t)(b0 + 2) * Nn + node) * Dn);
    const float4* __restrict__ xr3 =
        reinterpret_cast<const float4*>(x + ((size_t)(b0 + 3) * Nn + node) * Dn);

    float s00 = 0.f, s01 = 0.f, s10 = 0.f, s11 = 0.f;
    float s20 = 0.f, s21 = 0.f, s30 = 0.f, s31 = 0.f;

#pragma unroll
    for (int k = 0; k < 4; ++k) {
        const int idx = k * 16 + gl;      // float4 index within the 256-float row
        float4 a0 = w0[idx];
        float4 a1 = w1[idx];
        float4 x0 = xr0[idx];
        float4 x1 = xr1[idx];
        float4 x2 = xr2[idx];
        float4 x3 = xr3[idx];
        s00 += dot4(x0, a0); s01 += dot4(x0, a1);
        s10 += dot4(x1, a0); s11 += dot4(x1, a1);
        s20 += dot4(x2, a0); s21 += dot4(x2, a1);
        s30 += dot4(x3, a0); s31 += dot4(x3, a1);
    }

    // reduce each sum across the 16-lane group (xor 1,2,4,8 stay in-group)
#pragma unroll
    for (int off = 8; off >= 1; off >>= 1) {
        s00 += __shfl_xor(s00, off, 64);
        s01 += __shfl_xor(s01, off, 64);
        s10 += __shfl_xor(s10, off, 64);
        s11 += __shfl_xor(s11, off, 64);
        s20 += __shfl_xor(s20, off, 64);
        s21 += __shfl_xor(s21, off, 64);
        s30 += __shfl_xor(s30, off, 64);
        s31 += __shfl_xor(s31, off, 64);
    }

    if (gl == 0) {
        const float2 bj = *reinterpret_cast<const float2*>(bias + j * Pn);
        float2 o0 = make_float2(s00 + bj.x, s01 + bj.y);
        float2 o1 = make_float2(s10 + bj.x, s11 + bj.y);
        float2 o2 = make_float2(s20 + bj.x, s21 + bj.y);
        float2 o3 = make_float2(s30 + bj.x, s31 + bj.y);
        *reinterpret_cast<float2*>(out + ((size_t)(b0 + 0) * Jn + j) * Pn) = o0;
        *reinterpret_cast<float2*>(out + ((size_t)(b0 + 1) * Jn + j) * Pn) = o1;
        *reinterpret_cast<float2*>(out + ((size_t)(b0 + 2) * Jn + j) * Pn) = o2;
        *reinterpret_cast<float2*>(out + ((size_t)(b0 + 3) * Jn + j) * Pn) = o3;
    }
}

extern "C" void kernel_launch(void* const* d_in, const int* in_sizes, int n_in,
                              void* d_out, int out_size, void* d_ws, size_t ws_size,
                              hipStream_t stream) {
    const float* x    = (const float*)d_in[0];
    const float* W    = (const float*)d_in[1];
    const float* bias = (const float*)d_in[2];
    const int*   nfj  = (const int*)d_in[3];
    float* out = (float*)d_out;

    dim3 grid(Bn / 64, Jn);   // (256, 23): each block does 64 b x 1 j
    detok_kernel<<<grid, 256, 0, stream>>>(x, W, bias, nfj, out);
}